// Round 2
// baseline (313.009 us; speedup 1.0000x reference)
//
#include <hip/hip_runtime.h>

// SimpleGraphSAGE on MI355X — round 2.
// dst = repeat(arange(N),16) -> node i's edges are src[16i..16i+16), deg==16
// -> SpMM is a plain mean over 16 neighbor rows.
//
// Mapping change vs round 1 (which was LDS-pipe-bound at ~87us/layer):
//   matmul uses lane = node. W[k][j] is lane-uniform -> scalar s_load (SMEM
//   pipe), inputs live in VGPRs via a tiny padded-LDS transpose. LDS traffic
//   drops ~40x; kernel should be VALU-FMA-bound (~10.4us/layer floor).

#define NN   100000
#define DEG  16
#define F    64
#define NPB  64        // nodes per block; block = 64 threads = 1 wave
#define STR  65        // padded LDS row stride (2-way bank alias = free)

// One k-half of the matmul: acc[j] += buf_in[lane][k] * W[kbase+k][j]
template<int KHALF>
__device__ __forceinline__ void mm_half(const float* __restrict__ W,
                                        const float* __restrict__ buf,
                                        int lane, float acc[F])
{
    #pragma unroll 1
    for (int kc = 0; kc < F; kc += 8) {
        float ink[8];
        #pragma unroll
        for (int t = 0; t < 8; ++t)
            ink[t] = buf[lane * STR + kc + t];      // 2-way alias, free
        #pragma unroll
        for (int t = 0; t < 8; ++t) {
            const float* Wr = W + (KHALF + kc + t) * F;  // lane-uniform
            #pragma unroll
            for (int j = 0; j < F; ++j)
                acc[j] = fmaf(ink[t], Wr[j], acc[j]);    // SGPR W operand
        }
    }
}

template<bool RELU>
__global__ __launch_bounds__(64)
void sage_layer(const float* __restrict__ feat,   // [NN, F]
                const float* __restrict__ W,      // [2F, F]
                const float* __restrict__ bias,   // [F]
                const int*   __restrict__ src,    // [NN*DEG]
                float*       __restrict__ out)    // [NN, F]
{
    __shared__ __align__(16) float buf[NPB * STR];   // 16.6 KB

    const int lane   = threadIdx.x;          // 0..63
    const int node0  = blockIdx.x * NPB;
    const int mynode = node0 + lane;

    float acc[F];
    #pragma unroll
    for (int j = 0; j < F; ++j) acc[j] = bias[j];    // uniform -> s_load

    // ---- Phase A: stage self rows (lane = feature, coalesced 256B) ----
    for (int m = 0; m < NPB; ++m) {
        const int node = node0 + m;                  // uniform
        float v = 0.f;
        if (node < NN) v = feat[node * F + lane];
        buf[m * STR + lane] = v;
    }
    __syncthreads();
    mm_half<0>(W, buf, lane, acc);                   // k = 0..63
    __syncthreads();

    // ---- Phase B: stage neighbor means ----
    for (int m = 0; m < NPB; ++m) {
        const int node = node0 + m;                  // uniform
        float s = 0.f;
        if (node < NN) {
            const int* sp = src + node * DEG;        // uniform -> s_load idx
            #pragma unroll
            for (int n = 0; n < DEG; ++n)
                s += feat[sp[n] * F + lane];         // coalesced 256B rows
            s *= (1.0f / DEG);
        }
        buf[m * STR + lane] = s;
    }
    __syncthreads();
    mm_half<F>(W, buf, lane, acc);                   // k = 64..127
    __syncthreads();

    // ---- Epilogue: transpose through LDS for coalesced stores ----
    #pragma unroll
    for (int j = 0; j < F; ++j) {
        float r = acc[j];
        if (RELU) r = fmaxf(r, 0.f);
        buf[lane * STR + j] = r;
    }
    __syncthreads();
    for (int m = 0; m < NPB; ++m) {
        const int node = node0 + m;
        if (node < NN)
            out[node * F + lane] = buf[m * STR + lane];  // coalesced 256B
    }
}

extern "C" void kernel_launch(void* const* d_in, const int* in_sizes, int n_in,
                              void* d_out, int out_size, void* d_ws, size_t ws_size,
                              hipStream_t stream) {
    const float* x   = (const float*)d_in[0];
    const float* W1  = (const float*)d_in[1];
    const float* b1  = (const float*)d_in[2];
    const float* W2  = (const float*)d_in[3];
    const float* b2  = (const float*)d_in[4];
    const int*   src = (const int*)d_in[5];
    // d_in[6] = dst, unused: dst[e] == e / DEG by construction.

    float* h   = (float*)d_ws;    // [NN * F] fp32 = 25.6 MB
    float* out = (float*)d_out;

    const int blocks = (NN + NPB - 1) / NPB;   // 1563
    sage_layer<true ><<<blocks, 64, 0, stream>>>(x, W1, b1, src, h);
    sage_layer<false><<<blocks, 64, 0, stream>>>(h,  W2, b2, src, out);
}

// Round 3
// 236.027 us; speedup vs baseline: 1.3262x; 1.3262x over previous
//
#include <hip/hip_runtime.h>

// SimpleGraphSAGE on MI355X — round 3.
// dst = repeat(arange(N),16) -> node i's edges are src[16i..16i+16), deg==16
// -> SpMM is a plain mean over 16 neighbor rows.
//
// Round-1 (lane=col, LDS-broadcast matmul): LDS-pipe-bound, 87us/layer.
// Round-2 (lane=node, SGPR-W matmul, 1-wave blocks): correct idea, but only
//   1563 waves total -> latency-bound at 122us/layer (occupancy 16%).
// Round-3: keep SGPR-W matmul, restore wave count via j-split:
//   block = 64 nodes, 4 waves; gather stages k-major LDS buf[128][65];
//   matmul: lane=node, wave w owns 16 output columns. 6250 waves, 4 blk/CU.

#define NN   100000
#define DEG  16
#define F    64
#define KDIM 128      // 2*F
#define NPB  64       // nodes per block
#define STR  65       // LDS row stride in floats (2-way bank alias = free)
#define JPW  16       // output columns per wave

template<bool RELU>
__global__ __launch_bounds__(256, 4)
void sage_layer(const float* __restrict__ feat,   // [NN, F]
                const float* __restrict__ W,      // [KDIM, F]
                const float* __restrict__ bias,   // [F]
                const int*   __restrict__ src,    // [NN*DEG]
                float*       __restrict__ out)    // [NN, F]
{
    __shared__ float buf[KDIM][STR];   // k-major, 33.3 KB -> 4 blocks/CU

    const int tid   = threadIdx.x;
    const int lane  = tid & 63;
    // Force wave id into an SGPR so node / j0 / W addresses are provably
    // uniform -> neighbor indices, bias and W rows become s_load (SMEM pipe).
    const int wave  = __builtin_amdgcn_readfirstlane(tid >> 6);
    const int node0 = blockIdx.x * NPB;

    // ---- Gather phase: lane = feature column, wave stages 16 nodes ----
    #pragma unroll 2
    for (int m = 0; m < NPB / 4; ++m) {
        const int n    = wave * (NPB / 4) + m;   // uniform
        const int node = node0 + n;              // uniform
        if (node < NN) {
            buf[lane][n] = feat[node * F + lane];          // self, coalesced
            const int* sp = src + node * DEG;              // uniform -> s_load
            float s = 0.f;
            #pragma unroll
            for (int e = 0; e < DEG; ++e)
                s += feat[sp[e] * F + lane];               // coalesced 256B row
            buf[F + lane][n] = s * (1.0f / DEG);
        }
    }
    __syncthreads();

    // ---- Matmul phase: lane = node, wave w owns j in [16w, 16w+16) ----
    const int j0 = wave * JPW;                   // uniform
    float acc[JPW];
    #pragma unroll
    for (int j = 0; j < JPW; ++j) acc[j] = bias[j0 + j];   // s_load

    #pragma unroll 4
    for (int k = 0; k < KDIM; ++k) {
        const float v = buf[k][lane];            // ds_read_b32, 2-way = free
        const float* Wr = W + k * F + j0;        // uniform -> s_load_dwordx8 x2
        #pragma unroll
        for (int j = 0; j < JPW; ++j)
            acc[j] = fmaf(v, Wr[j], acc[j]);     // VGPR x SGPR fmac
    }

    const int node = node0 + lane;
    if (node < NN) {
        float4* op = (float4*)(out + node * F + j0);   // 16B aligned
        #pragma unroll
        for (int t = 0; t < 4; ++t) {
            float4 r = make_float4(acc[4 * t], acc[4 * t + 1],
                                   acc[4 * t + 2], acc[4 * t + 3]);
            if (RELU) {
                r.x = fmaxf(r.x, 0.f); r.y = fmaxf(r.y, 0.f);
                r.z = fmaxf(r.z, 0.f); r.w = fmaxf(r.w, 0.f);
            }
            op[t] = r;
        }
    }
}

extern "C" void kernel_launch(void* const* d_in, const int* in_sizes, int n_in,
                              void* d_out, int out_size, void* d_ws, size_t ws_size,
                              hipStream_t stream) {
    const float* x   = (const float*)d_in[0];
    const float* W1  = (const float*)d_in[1];
    const float* b1  = (const float*)d_in[2];
    const float* W2  = (const float*)d_in[3];
    const float* b2  = (const float*)d_in[4];
    const int*   src = (const int*)d_in[5];
    // d_in[6] = dst, unused: dst[e] == e / DEG by construction.

    float* h   = (float*)d_ws;    // [NN * F] fp32 = 25.6 MB
    float* out = (float*)d_out;

    const int blocks = (NN + NPB - 1) / NPB;   // 1563
    sage_layer<true ><<<blocks, 256, 0, stream>>>(x, W1, b1, src, h);
    sage_layer<false><<<blocks, 256, 0, stream>>>(h,  W2, b2, src, out);
}

// Round 4
// 214.991 us; speedup vs baseline: 1.4559x; 1.0978x over previous
//
#include <hip/hip_runtime.h>

// SimpleGraphSAGE on MI355X — round 4.
// dst = repeat(arange(N),16) -> node i's edges are src[16i..16i+16), deg==16.
//
// History: R1 85us/layer (LDS-pipe-bound matmul), R2 122us (latency, 1563
// waves), R3 83us/layer (SGPR-W matmul; gather-fetch-bound).
// R3 analysis: FETCH=188MB/dispatch == the L2-miss floor for 256B fp32 rows
// (each row needed by ~7.05 of 8 XCDs; 100k*7.05*256B = 180MB). Only lever
// left on that pipe: fewer bytes/row -> gather in BF16 (128B rows).
// Numerics: bf16 eps 2^-9 through mean-of-16 and K=64 dot with |W|<=0.088
// adds ~1e-3 absmax vs 1.88e-2 threshold.

#define NN   100000
#define DEG  16
#define F    64
#define KDIM 128
#define NPB  64       // nodes per block
#define STR  65       // LDS row stride (2-way bank alias = free)
#define JPW  16       // output columns per wave
#define EDG  (NN * DEG)

__device__ __forceinline__ ushort f2bf(float f) {        // RNE
    unsigned u = __float_as_uint(f);
    return (ushort)((u + 0x7fffu + ((u >> 16) & 1u)) >> 16);
}
__device__ __forceinline__ float bf2f(ushort u) {
    return __uint_as_float(((unsigned)u) << 16);
}

__global__ __launch_bounds__(256)
void cvt_f32_bf16(const float* __restrict__ in, ushort* __restrict__ out, int n4)
{
    int i = blockIdx.x * 256 + threadIdx.x;
    if (i < n4) {
        float4 v = ((const float4*)in)[i];
        ushort4 o;
        o.x = f2bf(v.x); o.y = f2bf(v.y); o.z = f2bf(v.z); o.w = f2bf(v.w);
        ((ushort4*)out)[i] = o;
    }
}

// ---------------- bf16-gather layer ----------------
template<bool RELU, bool EMIT_BF16>
__global__ __launch_bounds__(256, 4)
void sage_layer_bf(const float*  __restrict__ self_f32,  // [NN,F]
                   const ushort* __restrict__ gat_bf16,  // [NN,F] bf16 bits
                   const float*  __restrict__ W,         // [KDIM,F]
                   const float*  __restrict__ bias,      // [F]
                   const int*    __restrict__ src,       // [EDG]
                   float*        __restrict__ out_f32,   // [NN,F]
                   ushort*       __restrict__ out_bf16)  // [NN,F] or null
{
    __shared__ float buf[KDIM][STR];       // 33.3 KB
    __shared__ int   idx_lds[NPB * DEG];   // 4 KB

    const int tid   = threadIdx.x;
    const int lane  = tid & 63;
    const int wave  = __builtin_amdgcn_readfirstlane(tid >> 6);
    const int node0 = blockIdx.x * NPB;

    // Phase 0: stage this block's 1024 edge indices (coalesced int4).
    // Thread tid covers idx_lds[4t..4t+4) == its own wave's node range, so
    // no barrier is needed before the gather (wave-internal lgkm ordering).
    {
        const int e0 = node0 * DEG + tid * 4;
        int4 v = make_int4(0, 0, 0, 0);
        if (e0 < EDG) v = *(const int4*)(src + e0);   // EDG % 4 == 0
        *(int4*)&idx_lds[tid * 4] = v;
    }

    // Self rows: lane = feature, wave stages its 16 nodes (coalesced 256B).
    #pragma unroll 4
    for (int m = 0; m < NPB / 4; ++m) {
        const int n    = wave * (NPB / 4) + m;
        const int node = node0 + n;
        float v = 0.f;
        if (node < NN) v = self_f32[node * F + lane];
        buf[lane][n] = v;
    }

    // Neighbor means: indices from LDS (broadcast ds_read), bf16 row loads.
    #pragma unroll 2
    for (int m = 0; m < NPB / 4; ++m) {
        const int n    = wave * (NPB / 4) + m;
        const int node = node0 + n;
        float s = 0.f;
        if (node < NN) {
            const int* ip = &idx_lds[n * DEG];
            float s0 = 0.f, s1 = 0.f, s2 = 0.f, s3 = 0.f;
            #pragma unroll
            for (int e = 0; e < DEG; e += 4) {
                const int i0 = ip[e + 0], i1 = ip[e + 1];
                const int i2 = ip[e + 2], i3 = ip[e + 3];
                s0 += bf2f(gat_bf16[i0 * F + lane]);   // 128B coalesced row
                s1 += bf2f(gat_bf16[i1 * F + lane]);
                s2 += bf2f(gat_bf16[i2 * F + lane]);
                s3 += bf2f(gat_bf16[i3 * F + lane]);
            }
            s = (s0 + s1) + (s2 + s3);
        }
        buf[F + lane][n] = s * (1.0f / DEG);
    }
    __syncthreads();

    // Matmul: lane = node, wave owns j in [16w,16w+16). W row wave-uniform
    // -> s_load; buf[k][lane] ds_read_b32 2-way alias = free.
    const int j0 = wave * JPW;
    float acc[JPW];
    #pragma unroll
    for (int j = 0; j < JPW; ++j) acc[j] = bias[j0 + j];

    #pragma unroll 4
    for (int k = 0; k < KDIM; ++k) {
        const float v = buf[k][lane];
        const float* Wr = W + k * F + j0;
        #pragma unroll
        for (int j = 0; j < JPW; ++j)
            acc[j] = fmaf(v, Wr[j], acc[j]);
    }

    const int node = node0 + lane;
    if (node < NN) {
        if (RELU) {
            #pragma unroll
            for (int j = 0; j < JPW; ++j) acc[j] = fmaxf(acc[j], 0.f);
        }
        float4* op = (float4*)(out_f32 + node * F + j0);
        #pragma unroll
        for (int t = 0; t < 4; ++t)
            op[t] = make_float4(acc[4 * t], acc[4 * t + 1],
                                acc[4 * t + 2], acc[4 * t + 3]);
        if (EMIT_BF16) {
            uint4 p0, p1;
            unsigned* pw = &p0.x;
            #pragma unroll
            for (int t = 0; t < 8; ++t)
                (t < 4 ? (&p0.x)[t] : (&p1.x)[t - 4]) =
                    (unsigned)f2bf(acc[2 * t]) |
                    ((unsigned)f2bf(acc[2 * t + 1]) << 16);
            (void)pw;
            uint4* ob = (uint4*)(out_bf16 + node * F + j0);  // 32B aligned
            ob[0] = p0; ob[1] = p1;
        }
    }
}

// ---------------- fallback (round-3, all-fp32) ----------------
template<bool RELU>
__global__ __launch_bounds__(256, 4)
void sage_layer_f32(const float* __restrict__ feat,
                    const float* __restrict__ W,
                    const float* __restrict__ bias,
                    const int*   __restrict__ src,
                    float*       __restrict__ out)
{
    __shared__ float buf[KDIM][STR];
    const int tid   = threadIdx.x;
    const int lane  = tid & 63;
    const int wave  = __builtin_amdgcn_readfirstlane(tid >> 6);
    const int node0 = blockIdx.x * NPB;

    #pragma unroll 2
    for (int m = 0; m < NPB / 4; ++m) {
        const int n    = wave * (NPB / 4) + m;
        const int node = node0 + n;
        if (node < NN) {
            buf[lane][n] = feat[node * F + lane];
            const int* sp = src + node * DEG;
            float s = 0.f;
            #pragma unroll
            for (int e = 0; e < DEG; ++e) s += feat[sp[e] * F + lane];
            buf[F + lane][n] = s * (1.0f / DEG);
        }
    }
    __syncthreads();

    const int j0 = wave * JPW;
    float acc[JPW];
    #pragma unroll
    for (int j = 0; j < JPW; ++j) acc[j] = bias[j0 + j];
    #pragma unroll 4
    for (int k = 0; k < KDIM; ++k) {
        const float v = buf[k][lane];
        const float* Wr = W + k * F + j0;
        #pragma unroll
        for (int j = 0; j < JPW; ++j) acc[j] = fmaf(v, Wr[j], acc[j]);
    }
    const int node = node0 + lane;
    if (node < NN) {
        float4* op = (float4*)(out + node * F + j0);
        #pragma unroll
        for (int t = 0; t < 4; ++t) {
            float4 r = make_float4(acc[4 * t], acc[4 * t + 1],
                                   acc[4 * t + 2], acc[4 * t + 3]);
            if (RELU) {
                r.x = fmaxf(r.x, 0.f); r.y = fmaxf(r.y, 0.f);
                r.z = fmaxf(r.z, 0.f); r.w = fmaxf(r.w, 0.f);
            }
            op[t] = r;
        }
    }
}

extern "C" void kernel_launch(void* const* d_in, const int* in_sizes, int n_in,
                              void* d_out, int out_size, void* d_ws, size_t ws_size,
                              hipStream_t stream) {
    const float* x   = (const float*)d_in[0];
    const float* W1  = (const float*)d_in[1];
    const float* b1  = (const float*)d_in[2];
    const float* W2  = (const float*)d_in[3];
    const float* b2  = (const float*)d_in[4];
    const int*   src = (const int*)d_in[5];

    float* out = (float*)d_out;
    const int blocks = (NN + NPB - 1) / NPB;   // 1563

    const size_t hF32 = (size_t)NN * F * sizeof(float);   // 25.6 MB
    const size_t hBF  = (size_t)NN * F * sizeof(ushort);  // 12.8 MB

    if (ws_size >= hF32 + 2 * hBF) {
        float*  h_f32  = (float*)d_ws;
        ushort* x_bf16 = (ushort*)((char*)d_ws + hF32);
        ushort* h_bf16 = (ushort*)((char*)d_ws + hF32 + hBF);

        const int n4 = NN * F / 4;
        cvt_f32_bf16<<<(n4 + 255) / 256, 256, 0, stream>>>(x, x_bf16, n4);
        sage_layer_bf<true,  true ><<<blocks, 256, 0, stream>>>(
            x, x_bf16, W1, b1, src, h_f32, h_bf16);
        sage_layer_bf<false, false><<<blocks, 256, 0, stream>>>(
            h_f32, h_bf16, W2, b2, src, out, nullptr);
    } else {
        float* h = (float*)d_ws;
        sage_layer_f32<true ><<<blocks, 256, 0, stream>>>(x, W1, b1, src, h);
        sage_layer_f32<false><<<blocks, 256, 0, stream>>>(h, W2, b2, src, out);
    }
}